// Round 8
// baseline (224.080 us; speedup 1.0000x reference)
//
#include <hip/hip_runtime.h>

#define N_TOK 16384
#define D 64
#define NC 512
#define KSEL 16

// ---------------- kernel P0: zero out + zero hist + center norms ----------------
__global__ void prep_kernel(float4* __restrict__ out4, int* __restrict__ hist,
                            const float* __restrict__ ctrs, float* __restrict__ c2) {
    int i = blockIdx.x * 256 + threadIdx.x;
    out4[i] = make_float4(0.f, 0.f, 0.f, 0.f);
    if (i < NC) {
        const float4* row = (const float4*)(ctrs + i * D);
        float s = 0.f;
        #pragma unroll
        for (int q = 0; q < D / 4; ++q) {
            float4 v = row[q];
            s += v.x * v.x + v.y * v.y + v.z * v.z + v.w * v.w;
        }
        c2[i] = s;
    } else if (i < 2 * NC) {
        hist[i - NC] = 0;
    }
}

__device__ __forceinline__ unsigned fkey(float f) {
    unsigned u = __float_as_uint(f);
    return (u & 0x80000000u) ? ~u : (u | 0x80000000u);
}
__device__ __forceinline__ float funkey(unsigned k) {
    unsigned u = (k & 0x80000000u) ? (k & 0x7fffffffu) : ~k;
    return __uint_as_float(u);
}

// ---------------- kernel B: dist + top-16 + softmax, lane = token ----------------
// 512 threads = 8 waves; lane L <-> token base+L. Wave wi owns the contiguous
// center block [wi*64, wi*64+64) -- the center pointer is WAVE-UNIFORM, so all
// center-row reads become s_load (scalar pipe) feeding v_fmac v,s,v. No LDS in
// the hot loop. Selection = streaming sorted top-16 in registers.
// Keys: fkey(score) with low 9 bits = center id (globally unique -> exact merge).
__global__ __launch_bounds__(512) void topk8_kernel(
    const float* __restrict__ x, const float* __restrict__ ctrs,
    const float* __restrict__ c2, float* __restrict__ scores,
    int* __restrict__ sidx, int* __restrict__ hist) {
    __shared__ __align__(16) unsigned char pool[33792];
    float* xs = (float*)pool;                 // [64][68]  17408 B (staging only)
    unsigned* mb = (unsigned*)pool;           // [64][132] 33792 B, overlays xs
    __shared__ int lhist[NC];

    const int t = threadIdx.x;
    const int lane = t & 63;
    const int wi = t >> 6;
    const int wiu = __builtin_amdgcn_readfirstlane(wi);
    const int base = blockIdx.x * 64;

    if (t < NC) lhist[t] = 0;

    // stage x tile -> xs (stride 68: conflict-free b128 per-lane reads)
    #pragma unroll
    for (int i = 0; i < 2; ++i) {
        int e = t + 512 * i;
        int r = e >> 4, j = e & 15;
        float4 v = *(const float4*)(x + (base + r) * D + j * 4);
        *(float4*)(xs + r * 68 + j * 4) = v;
    }
    __syncthreads();

    // own token's x row -> 64 VGPRs
    float xr[64];
    #pragma unroll
    for (int q = 0; q < 16; ++q) {
        float4 v = *(const float4*)(xs + lane * 68 + q * 4);
        xr[4 * q + 0] = v.x; xr[4 * q + 1] = v.y;
        xr[4 * q + 2] = v.z; xr[4 * q + 3] = v.w;
    }
    __syncthreads();   // all xs reads done -> mb overlay safe later

    // running top-16, sorted descending; all real keys > 0
    unsigned run[KSEL];
    #pragma unroll
    for (int r = 0; r < KSEL; ++r) run[r] = 0u;

    const float* crow = ctrs + wiu * 64 * D;   // wave-uniform base
    const float* c2p = c2 + wiu * 64;

    #pragma unroll 2
    for (int jc = 0; jc < 64; ++jc) {
        const float* row = crow + jc * D;      // uniform -> s_load
        float a0 = 0.f, a1 = 0.f;
        #pragma unroll
        for (int q = 0; q < 8; ++q) {
            float4 w0 = *(const float4*)(row + q * 8);
            float4 w1 = *(const float4*)(row + q * 8 + 4);
            a0 = fmaf(xr[8*q+0], w0.x, a0); a0 = fmaf(xr[8*q+1], w0.y, a0);
            a0 = fmaf(xr[8*q+2], w0.z, a0); a0 = fmaf(xr[8*q+3], w0.w, a0);
            a1 = fmaf(xr[8*q+4], w1.x, a1); a1 = fmaf(xr[8*q+5], w1.y, a1);
            a1 = fmaf(xr[8*q+6], w1.z, a1); a1 = fmaf(xr[8*q+7], w1.w, a1);
        }
        int cg = wiu * 64 + jc;
        float sc = fmaf(2.f, a0 + a1, -c2p[jc]);   // uniform -> s_load
        unsigned k = (fkey(sc) & 0xFFFFFE00u) | (unsigned)cg;
        if (k > run[KSEL - 1]) {       // rare; exec-masked cascade
            #pragma unroll
            for (int r = 0; r < KSEL; ++r) {
                unsigned mx = run[r] > k ? run[r] : k;
                unsigned mn = run[r] > k ? k : run[r];
                run[r] = mx; k = mn;
            }
        }
    }

    {
        uint4* dst = (uint4*)(mb + lane * 132 + wi * 16);
        dst[0] = make_uint4(run[0], run[1], run[2], run[3]);
        dst[1] = make_uint4(run[4], run[5], run[6], run[7]);
        dst[2] = make_uint4(run[8], run[9], run[10], run[11]);
        dst[3] = make_uint4(run[12], run[13], run[14], run[15]);
    }
    __syncthreads();

    if (wi == 0) {  // 8-way tournament merge per lane (= per token), exact
        unsigned h[8]; int pos[8];
        #pragma unroll
        for (int w = 0; w < 8; ++w) { pos[w] = 0; h[w] = mb[lane * 132 + w * 16]; }
        float vals[16]; int ids[16];
        #pragma unroll
        for (int r = 0; r < KSEL; ++r) {
            unsigned m = h[0];
            #pragma unroll
            for (int w = 1; w < 8; ++w) m = m > h[w] ? m : h[w];
            vals[r] = funkey(m);
            ids[r] = (int)(m & 511u);
            #pragma unroll
            for (int w = 0; w < 8; ++w) {
                if (h[w] == m) {  // unique keys -> exactly one hit
                    ++pos[w];
                    h[w] = (pos[w] < KSEL) ? mb[lane * 132 + w * 16 + pos[w]] : 0u;
                }
            }
        }
        float mx = vals[0];
        float e[16]; float sum = 0.f;
        #pragma unroll
        for (int r = 0; r < KSEL; ++r) { e[r] = __expf(vals[r] - mx); sum += e[r]; }
        float inv = 1.f / sum;
        int n = base + lane;
        #pragma unroll
        for (int q = 0; q < 4; ++q) {
            *(float4*)(scores + n * KSEL + 4 * q) =
                make_float4(e[4*q] * inv, e[4*q+1] * inv, e[4*q+2] * inv, e[4*q+3] * inv);
            *(int4*)(sidx + n * KSEL + 4 * q) =
                make_int4(ids[4*q], ids[4*q+1], ids[4*q+2], ids[4*q+3]);
        }
        #pragma unroll
        for (int r = 0; r < KSEL; ++r) atomicAdd(&lhist[ids[r]], 1);
    }
    __syncthreads();
    for (int i = t; i < NC; i += 512) { int hv = lhist[i]; if (hv) atomicAdd(&hist[i], hv); }
}

// ---------------- kernel S: prefix scan of hist (single block) ----------------
__global__ __launch_bounds__(512) void scan_kernel(const int* __restrict__ hist,
                                                   int* __restrict__ offs,
                                                   int* __restrict__ cursor) {
    __shared__ int buf[2][NC];
    int t = threadIdx.x;
    int self = hist[t];
    buf[0][t] = self;
    __syncthreads();
    int a = 0;
    for (int d = 1; d < NC; d <<= 1) {
        int val = buf[a][t] + (t >= d ? buf[a][t - d] : 0);
        buf[1 - a][t] = val;
        __syncthreads();
        a = 1 - a;
    }
    int incl = buf[a][t];
    int excl = incl - self;
    offs[t] = excl;
    cursor[t] = excl;
    if (t == NC - 1) offs[NC] = incl;
}

// ---------------- kernel P: counting-sort scatter, 256 blocks ----------------
// tokentab entry packs (c << 18) | e, where e = token*16 + slot (original order).
__global__ __launch_bounds__(256) void scatter4_kernel(
    const int* __restrict__ sidx, const float* __restrict__ scores,
    int* __restrict__ cursor, int* __restrict__ tokentab,
    float* __restrict__ scotab) {
    __shared__ int lh[NC];
    __shared__ int lbase[NC];
    const int t = threadIdx.x;
    for (int i = t; i < NC; i += 256) lh[i] = 0;
    __syncthreads();
    const int base_e = blockIdx.x * 1024;
    int myc[4];
    #pragma unroll
    for (int i = 0; i < 4; ++i) {
        int c = sidx[base_e + t + 256 * i];
        myc[i] = c;
        atomicAdd(&lh[c], 1);
    }
    __syncthreads();
    for (int i = t; i < NC; i += 256) {
        int h = lh[i];
        lbase[i] = h ? atomicAdd(&cursor[i], h) : 0;
        lh[i] = 0;
    }
    __syncthreads();
    #pragma unroll
    for (int i = 0; i < 4; ++i) {
        int e = base_e + t + 256 * i;
        int c = myc[i];
        int pos = lbase[c] + atomicAdd(&lh[c], 1);
        tokentab[pos] = (c << 18) | e;
        scotab[pos] = scores[e];
    }
}

// ---------------- kernel C: run-split affine mixing, atomic accumulate ----------
// 128-thread blocks (2 waves), launch_bounds(128,4): VGPR cap 128, live set ~95
// -> w[64] must stay in VGPRs. One wave per 32 center-sorted pairs; same-center
// runs share the W load. x rows via wave-uniform scalar loads; output via
// fire-and-forget f32 atomics.
__global__ __launch_bounds__(128, 4) void mix8_kernel(
    const float* __restrict__ x, const float* __restrict__ Wv,
    const float* __restrict__ Ov, const int* __restrict__ tokentab,
    const float* __restrict__ scotab, float* __restrict__ out) {
    const int lane = threadIdx.x & 63;
    const int gw = blockIdx.x * 2 + (threadIdx.x >> 6);   // 0..8191
    const int i0 = gw * 32;

    int word_v = tokentab[i0 + (lane & 31)];
    int sco_v = __float_as_int(scotab[i0 + (lane & 31)]);

    int ii = 0;
    #pragma unroll 1
    while (ii < 32) {
        const int c = __builtin_amdgcn_readlane(word_v, ii) >> 18;
        // end of this center-run
        int je = ii + 1;
        #pragma unroll 1
        while (je < 32 && (__builtin_amdgcn_readlane(word_v, je) >> 18) == c) ++je;

        // lane's W column -> registers
        float w[64];
        {
            const float* Wc = Wv + c * (D * D) + lane;
            #pragma unroll
            for (int g = 0; g < 64; ++g) w[g] = Wc[g * 64];
        }
        const float ovl = Ov[c * D + lane];

        #pragma unroll 1
        for (; ii < je; ++ii) {
            int word = __builtin_amdgcn_readlane(word_v, ii);
            float sc = __int_as_float(__builtin_amdgcn_readlane(sco_v, ii));
            int n = (word & 0x3FFFF) >> 4;
            const float* xr = x + n * D;      // uniform -> scalar loads
            float a0 = 0.f, a1 = 0.f, a2 = 0.f, a3 = 0.f;
            #pragma unroll
            for (int q = 0; q < 4; ++q) {
                float4 v0 = *(const float4*)(xr + 16 * q + 0);
                float4 v1 = *(const float4*)(xr + 16 * q + 4);
                float4 v2 = *(const float4*)(xr + 16 * q + 8);
                float4 v3 = *(const float4*)(xr + 16 * q + 12);
                a0 = fmaf(v0.x, w[16*q+0], a0);  a0 = fmaf(v0.y, w[16*q+1], a0);
                a0 = fmaf(v0.z, w[16*q+2], a0);  a0 = fmaf(v0.w, w[16*q+3], a0);
                a1 = fmaf(v1.x, w[16*q+4], a1);  a1 = fmaf(v1.y, w[16*q+5], a1);
                a1 = fmaf(v1.z, w[16*q+6], a1);  a1 = fmaf(v1.w, w[16*q+7], a1);
                a2 = fmaf(v2.x, w[16*q+8], a2);  a2 = fmaf(v2.y, w[16*q+9], a2);
                a2 = fmaf(v2.z, w[16*q+10], a2); a2 = fmaf(v2.w, w[16*q+11], a2);
                a3 = fmaf(v3.x, w[16*q+12], a3); a3 = fmaf(v3.y, w[16*q+13], a3);
                a3 = fmaf(v3.z, w[16*q+14], a3); a3 = fmaf(v3.w, w[16*q+15], a3);
            }
            float a = (a0 + a1) + (a2 + a3);
            unsafeAtomicAdd(out + n * D + lane, sc * (a + ovl));
        }
    }
}

extern "C" void kernel_launch(void* const* d_in, const int* in_sizes, int n_in,
                              void* d_out, int out_size, void* d_ws, size_t ws_size,
                              hipStream_t stream) {
    const float* x    = (const float*)d_in[0];
    const float* ctrs = (const float*)d_in[1];
    const float* Wv   = (const float*)d_in[2];
    const float* Ov   = (const float*)d_in[3];
    float* out = (float*)d_out;

    float* c2       = (float*)d_ws;                    // 512
    int*   hist     = (int*)d_ws + 512;                // 512
    int*   offs     = (int*)d_ws + 1024;               // 513 (reserve 1024)
    int*   cursor   = (int*)d_ws + 2048;               // 512 (reserve 512)
    float* scores   = (float*)d_ws + 2560;             // 262144
    int*   sidx     = (int*)d_ws + 2560 + 262144;      // 262144
    int*   tokentab = (int*)d_ws + 2560 + 2 * 262144;  // 262144
    float* scotab   = (float*)d_ws + 2560 + 3 * 262144;// 262144

    hipLaunchKernelGGL(prep_kernel, dim3(1024), dim3(256), 0, stream,
                       (float4*)out, hist, ctrs, c2);
    hipLaunchKernelGGL(topk8_kernel, dim3(N_TOK / 64), dim3(512), 0, stream,
                       x, ctrs, c2, scores, sidx, hist);
    hipLaunchKernelGGL(scan_kernel, dim3(1), dim3(512), 0, stream, hist, offs, cursor);
    hipLaunchKernelGGL(scatter4_kernel, dim3(256), dim3(256), 0, stream,
                       sidx, scores, cursor, tokentab, scotab);
    hipLaunchKernelGGL(mix8_kernel, dim3(4096), dim3(128), 0, stream,
                       x, Wv, Ov, tokentab, scotab, out);
}

// Round 9
// 196.335 us; speedup vs baseline: 1.1413x; 1.1413x over previous
//
#include <hip/hip_runtime.h>

#define N_TOK 16384
#define D 64
#define NC 512
#define KSEL 16

__device__ __forceinline__ unsigned fkey(float f) {
    unsigned u = __float_as_uint(f);
    return (u & 0x80000000u) ? ~u : (u | 0x80000000u);
}
__device__ __forceinline__ float funkey(unsigned k) {
    unsigned u = (k & 0x80000000u) ? (k & 0x7fffffffu) : ~k;
    return __uint_as_float(u);
}

// ---------------- kernel B: dist + top-16 + softmax ----------------
// 512 threads = 8 waves, 64 tokens/block, 256 blocks.
// GEMM: outer-product tiles. Thread (ty=wave, tc=lane) computes 8 tokens x 4
// centers; per k: 2 broadcast b128 (xa) + 1 striped b128 (cb) -> 32 fma.
// Phases of 256 centers; S-tile written to LDS (overlays csT), then wave wi
// streams its 8-c4 slice through the register top-16 cascade (token = lane).
// Keys: fkey(score) low 9 bits = center id (globally unique -> exact merge).
__global__ __launch_bounds__(512) void topk9_kernel(
    const float* __restrict__ x, const float* __restrict__ ctrs,
    float* __restrict__ scores, int* __restrict__ sidx, int* __restrict__ hist) {
    __shared__ __align__(16) unsigned char pool[88064];
    float* xsT = (float*)pool;                  // [64 k][68]        17408 B
    float* csT = (float*)(pool + 17408);        // [64 k][260] / Sb  66560 B
    float* Sb  = csT;                           // Sb[c4][tok*4+q], stride 260
    float* c2s = (float*)(pool + 83968);        // [512]              2048 B
    int* lhist = (int*)(pool + 86016);          // [512]              2048 B
    unsigned* mb = (unsigned*)(pool + 17408);   // [64][132] overlay on csT/Sb

    const int t = threadIdx.x;
    const int lane = t & 63;
    const int wi = t >> 6;
    const int base = blockIdx.x * 64;

    lhist[t] = 0;

    // c2: thread t computes ||ctrs[t]||^2
    {
        const float4* row = (const float4*)(ctrs + t * D);
        float s = 0.f;
        #pragma unroll
        for (int q = 0; q < 16; ++q) {
            float4 v = row[q];
            s += v.x * v.x + v.y * v.y + v.z * v.z + v.w * v.w;
        }
        c2s[t] = s;
    }

    // stage xsT[k][tok] (transpose; coalesced global reads)
    #pragma unroll
    for (int i = 0; i < 2; ++i) {
        int e = t + 512 * i;
        int r = e >> 4, j = e & 15;
        float4 v = *(const float4*)(x + (base + r) * D + 4 * j);
        xsT[(4 * j + 0) * 68 + r] = v.x;
        xsT[(4 * j + 1) * 68 + r] = v.y;
        xsT[(4 * j + 2) * 68 + r] = v.z;
        xsT[(4 * j + 3) * 68 + r] = v.w;
    }

    unsigned run[KSEL];
    #pragma unroll
    for (int r = 0; r < KSEL; ++r) run[r] = 0u;

    #pragma unroll 1
    for (int p = 0; p < 2; ++p) {
        __syncthreads();   // prev phase's Sb reads done; c2s/xsT ready (p=0)

        // stage csT[k][c] for 256 centers (conflict-free LDS writes)
        #pragma unroll
        for (int i = 0; i < 8; ++i) {
            int e = t + 512 * i;              // 0..4095 float4 units
            int cl = e & 255, j = e >> 8;     // j 0..15
            float4 v = *(const float4*)(ctrs + (p * 256 + cl) * D + 4 * j);
            csT[(4 * j + 0) * 260 + cl] = v.x;
            csT[(4 * j + 1) * 260 + cl] = v.y;
            csT[(4 * j + 2) * 260 + cl] = v.z;
            csT[(4 * j + 3) * 260 + cl] = v.w;
        }
        __syncthreads();

        // GEMM: 8 tokens (8*wi..) x 4 centers (4*lane..)
        float acc[8][4];
        #pragma unroll
        for (int i = 0; i < 8; ++i)
            #pragma unroll
            for (int q = 0; q < 4; ++q) acc[i][q] = 0.f;

        #pragma unroll 2
        for (int k = 0; k < 64; ++k) {
            const float* xrow = xsT + k * 68 + 8 * wi;    // wave-uniform
            float4 xa0 = *(const float4*)(xrow);
            float4 xa1 = *(const float4*)(xrow + 4);
            float4 cb = *(const float4*)(csT + k * 260 + 4 * lane);
            float xa[8] = {xa0.x, xa0.y, xa0.z, xa0.w, xa1.x, xa1.y, xa1.z, xa1.w};
            #pragma unroll
            for (int i = 0; i < 8; ++i) {
                acc[i][0] = fmaf(xa[i], cb.x, acc[i][0]);
                acc[i][1] = fmaf(xa[i], cb.y, acc[i][1]);
                acc[i][2] = fmaf(xa[i], cb.z, acc[i][2]);
                acc[i][3] = fmaf(xa[i], cb.w, acc[i][3]);
            }
        }
        __syncthreads();   // all csT reads done -> Sb overlay safe

        #pragma unroll
        for (int i = 0; i < 8; ++i)
            *(float4*)(Sb + lane * 260 + (8 * wi + i) * 4) =
                make_float4(acc[i][0], acc[i][1], acc[i][2], acc[i][3]);
        __syncthreads();

        // selection: wave wi streams c4 slice [8wi, 8wi+8); token = lane
        #pragma unroll
        for (int s8 = 0; s8 < 8; ++s8) {
            int c4 = wi * 8 + s8;
            float4 sv = *(const float4*)(Sb + c4 * 260 + 4 * lane);
            float4 cq = *(const float4*)(c2s + p * 256 + 4 * c4);  // uniform
            float sq[4] = {fmaf(2.f, sv.x, -cq.x), fmaf(2.f, sv.y, -cq.y),
                           fmaf(2.f, sv.z, -cq.z), fmaf(2.f, sv.w, -cq.w)};
            #pragma unroll
            for (int q = 0; q < 4; ++q) {
                unsigned cg = (unsigned)(p * 256 + 4 * c4 + q);
                unsigned k = (fkey(sq[q]) & 0xFFFFFE00u) | cg;
                if (k > run[KSEL - 1]) {
                    #pragma unroll
                    for (int r = 0; r < KSEL; ++r) {
                        unsigned mx = run[r] > k ? run[r] : k;
                        unsigned mn = run[r] > k ? k : run[r];
                        run[r] = mx; k = mn;
                    }
                }
            }
        }
    }

    __syncthreads();   // Sb reads done -> mb overlay safe
    {
        uint4* dst = (uint4*)(mb + lane * 132 + wi * 16);
        dst[0] = make_uint4(run[0], run[1], run[2], run[3]);
        dst[1] = make_uint4(run[4], run[5], run[6], run[7]);
        dst[2] = make_uint4(run[8], run[9], run[10], run[11]);
        dst[3] = make_uint4(run[12], run[13], run[14], run[15]);
    }
    __syncthreads();

    if (wi == 0) {  // 8-way tournament merge per lane (= per token), exact
        unsigned h[8]; int pos[8];
        #pragma unroll
        for (int w = 0; w < 8; ++w) { pos[w] = 0; h[w] = mb[lane * 132 + w * 16]; }
        float vals[16]; int ids[16];
        #pragma unroll
        for (int r = 0; r < KSEL; ++r) {
            unsigned m = h[0];
            #pragma unroll
            for (int w = 1; w < 8; ++w) m = m > h[w] ? m : h[w];
            vals[r] = funkey(m);
            ids[r] = (int)(m & 511u);
            #pragma unroll
            for (int w = 0; w < 8; ++w) {
                if (h[w] == m) {  // unique keys -> exactly one hit
                    ++pos[w];
                    h[w] = (pos[w] < KSEL) ? mb[lane * 132 + w * 16 + pos[w]] : 0u;
                }
            }
        }
        float mx = vals[0];
        float e[16]; float sum = 0.f;
        #pragma unroll
        for (int r = 0; r < KSEL; ++r) { e[r] = __expf(vals[r] - mx); sum += e[r]; }
        float inv = 1.f / sum;
        int n = base + lane;
        #pragma unroll
        for (int q = 0; q < 4; ++q) {
            *(float4*)(scores + n * KSEL + 4 * q) =
                make_float4(e[4*q] * inv, e[4*q+1] * inv, e[4*q+2] * inv, e[4*q+3] * inv);
            *(int4*)(sidx + n * KSEL + 4 * q) =
                make_int4(ids[4*q], ids[4*q+1], ids[4*q+2], ids[4*q+3]);
        }
        #pragma unroll
        for (int r = 0; r < KSEL; ++r) atomicAdd(&lhist[ids[r]], 1);
    }
    __syncthreads();
    { int hv = lhist[t]; if (hv) atomicAdd(&hist[t], hv); }
}

// ---------------- kernel S: prefix scan of hist (single block) ----------------
__global__ __launch_bounds__(512) void scan_kernel(const int* __restrict__ hist,
                                                   int* __restrict__ offs,
                                                   int* __restrict__ cursor) {
    __shared__ int buf[2][NC];
    int t = threadIdx.x;
    int self = hist[t];
    buf[0][t] = self;
    __syncthreads();
    int a = 0;
    for (int d = 1; d < NC; d <<= 1) {
        int val = buf[a][t] + (t >= d ? buf[a][t - d] : 0);
        buf[1 - a][t] = val;
        __syncthreads();
        a = 1 - a;
    }
    int incl = buf[a][t];
    int excl = incl - self;
    offs[t] = excl;
    cursor[t] = excl;
    if (t == NC - 1) offs[NC] = incl;
}

// ---------------- kernel P: counting-sort scatter, 256 blocks ----------------
// tokentab entry packs (c << 18) | e, where e = token*16 + slot (original order).
__global__ __launch_bounds__(256) void scatter4_kernel(
    const int* __restrict__ sidx, const float* __restrict__ scores,
    int* __restrict__ cursor, int* __restrict__ tokentab,
    float* __restrict__ scotab) {
    __shared__ int lh[NC];
    __shared__ int lbase[NC];
    const int t = threadIdx.x;
    for (int i = t; i < NC; i += 256) lh[i] = 0;
    __syncthreads();
    const int base_e = blockIdx.x * 1024;
    int myc[4];
    #pragma unroll
    for (int i = 0; i < 4; ++i) {
        int c = sidx[base_e + t + 256 * i];
        myc[i] = c;
        atomicAdd(&lh[c], 1);
    }
    __syncthreads();
    for (int i = t; i < NC; i += 256) {
        int h = lh[i];
        lbase[i] = h ? atomicAdd(&cursor[i], h) : 0;
        lh[i] = 0;
    }
    __syncthreads();
    #pragma unroll
    for (int i = 0; i < 4; ++i) {
        int e = base_e + t + 256 * i;
        int c = myc[i];
        int pos = lbase[c] + atomicAdd(&lh[c], 1);
        tokentab[pos] = (c << 18) | e;
        scotab[pos] = scores[e];
    }
}

// ---------------- kernel C: run-split affine mixing, atomic accumulate ----------
// 128-thread blocks (2 waves), launch_bounds(128,4): VGPR cap 128. One wave per
// 32 center-sorted pairs; same-center runs share the W load. x rows via
// wave-uniform scalar loads; output via fire-and-forget f32 atomics.
__global__ __launch_bounds__(128, 4) void mix8_kernel(
    const float* __restrict__ x, const float* __restrict__ Wv,
    const float* __restrict__ Ov, const int* __restrict__ tokentab,
    const float* __restrict__ scotab, float* __restrict__ out) {
    const int lane = threadIdx.x & 63;
    const int gw = blockIdx.x * 2 + (threadIdx.x >> 6);   // 0..8191
    const int i0 = gw * 32;

    int word_v = tokentab[i0 + (lane & 31)];
    int sco_v = __float_as_int(scotab[i0 + (lane & 31)]);

    int ii = 0;
    #pragma unroll 1
    while (ii < 32) {
        const int c = __builtin_amdgcn_readlane(word_v, ii) >> 18;
        // end of this center-run
        int je = ii + 1;
        #pragma unroll 1
        while (je < 32 && (__builtin_amdgcn_readlane(word_v, je) >> 18) == c) ++je;

        // lane's W column -> registers
        float w[64];
        {
            const float* Wc = Wv + c * (D * D) + lane;
            #pragma unroll
            for (int g = 0; g < 64; ++g) w[g] = Wc[g * 64];
        }
        const float ovl = Ov[c * D + lane];

        #pragma unroll 1
        for (; ii < je; ++ii) {
            int word = __builtin_amdgcn_readlane(word_v, ii);
            float sc = __int_as_float(__builtin_amdgcn_readlane(sco_v, ii));
            int n = (word & 0x3FFFF) >> 4;
            const float* xr = x + n * D;      // uniform -> scalar loads
            float a0 = 0.f, a1 = 0.f, a2 = 0.f, a3 = 0.f;
            #pragma unroll
            for (int q = 0; q < 4; ++q) {
                float4 v0 = *(const float4*)(xr + 16 * q + 0);
                float4 v1 = *(const float4*)(xr + 16 * q + 4);
                float4 v2 = *(const float4*)(xr + 16 * q + 8);
                float4 v3 = *(const float4*)(xr + 16 * q + 12);
                a0 = fmaf(v0.x, w[16*q+0], a0);  a0 = fmaf(v0.y, w[16*q+1], a0);
                a0 = fmaf(v0.z, w[16*q+2], a0);  a0 = fmaf(v0.w, w[16*q+3], a0);
                a1 = fmaf(v1.x, w[16*q+4], a1);  a1 = fmaf(v1.y, w[16*q+5], a1);
                a1 = fmaf(v1.z, w[16*q+6], a1);  a1 = fmaf(v1.w, w[16*q+7], a1);
                a2 = fmaf(v2.x, w[16*q+8], a2);  a2 = fmaf(v2.y, w[16*q+9], a2);
                a2 = fmaf(v2.z, w[16*q+10], a2); a2 = fmaf(v2.w, w[16*q+11], a2);
                a3 = fmaf(v3.x, w[16*q+12], a3); a3 = fmaf(v3.y, w[16*q+13], a3);
                a3 = fmaf(v3.z, w[16*q+14], a3); a3 = fmaf(v3.w, w[16*q+15], a3);
            }
            float a = (a0 + a1) + (a2 + a3);
            unsafeAtomicAdd(out + n * D + lane, sc * (a + ovl));
        }
    }
}

extern "C" void kernel_launch(void* const* d_in, const int* in_sizes, int n_in,
                              void* d_out, int out_size, void* d_ws, size_t ws_size,
                              hipStream_t stream) {
    const float* x    = (const float*)d_in[0];
    const float* ctrs = (const float*)d_in[1];
    const float* Wv   = (const float*)d_in[2];
    const float* Ov   = (const float*)d_in[3];
    float* out = (float*)d_out;

    int*   hist     = (int*)d_ws + 512;                // 512 (c2 slot unused)
    int*   offs     = (int*)d_ws + 1024;               // 513 (reserve 1024)
    int*   cursor   = (int*)d_ws + 2048;               // 512 (reserve 512)
    float* scores   = (float*)d_ws + 2560;             // 262144
    int*   sidx     = (int*)d_ws + 2560 + 262144;      // 262144
    int*   tokentab = (int*)d_ws + 2560 + 2 * 262144;  // 262144
    float* scotab   = (float*)d_ws + 2560 + 3 * 262144;// 262144

    hipMemsetAsync(out, 0, (size_t)N_TOK * D * sizeof(float), stream);
    hipMemsetAsync(hist, 0, NC * sizeof(int), stream);
    hipLaunchKernelGGL(topk9_kernel, dim3(N_TOK / 64), dim3(512), 0, stream,
                       x, ctrs, scores, sidx, hist);
    hipLaunchKernelGGL(scan_kernel, dim3(1), dim3(512), 0, stream, hist, offs, cursor);
    hipLaunchKernelGGL(scatter4_kernel, dim3(256), dim3(256), 0, stream,
                       sidx, scores, cursor, tokentab, scotab);
    hipLaunchKernelGGL(mix8_kernel, dim3(4096), dim3(128), 0, stream,
                       x, Wv, Ov, tokentab, scotab, out);
}